// Round 15
// baseline (996.501 us; speedup 1.0000x reference)
//
#include <hip/hip_runtime.h>
#include <math.h>

#define CC    192
#define TT    8
#define HH    56
#define WWD   56
#define PP    3136      // H*W
#define NTOK  100352    // 32*56*56
#define NSEQ  12544     // 4*56*56

typedef __attribute__((ext_vector_type(8))) short short8v;  // 8 bf16 (4 VGPR)
typedef __attribute__((ext_vector_type(4))) float f32x4;
using u16 = unsigned short;

__device__ __forceinline__ float gelu_f(float v) {
  return 0.5f * v * (1.0f + erff(v * 0.70710678f));
}

__device__ __forceinline__ u16 bf16hi(float f) {
  unsigned u = __builtin_bit_cast(unsigned, f);
  u += 0x7fffu + ((u >> 16) & 1u);
  return (u16)(u >> 16);
}
__device__ __forceinline__ float bf2f(u16 h) {
  unsigned u = ((unsigned)h) << 16;
  return __builtin_bit_cast(float, u);
}

__device__ __forceinline__ void split4(float4 v, uint2* ph, uint2* pl) {
  float vv[4] = {v.x, v.y, v.z, v.w};
  u16 hh[4], ll[4];
  #pragma unroll
  for (int u = 0; u < 4; ++u) {
    hh[u] = bf16hi(vv[u]);
    ll[u] = bf16hi(vv[u] - bf2f(hh[u]));
  }
  *ph = make_uint2((unsigned)hh[0] | ((unsigned)hh[1] << 16),
                   (unsigned)hh[2] | ((unsigned)hh[3] << 16));
  *pl = make_uint2((unsigned)ll[0] | ((unsigned)ll[1] << 16),
                   (unsigned)ll[2] | ((unsigned)ll[3] << 16));
}

// ---------------- weight split kernels ----------------
__global__ __launch_bounds__(256) void k_wsplit(const float* __restrict__ in,
    u16* __restrict__ hi, u16* __restrict__ lo, int K) {
  int idx = blockIdx.x * 256 + threadIdx.x;
  int total = CC * CC * K;
  if (idx >= total) return;
  int i = idx % CC;
  int rest = idx / CC;
  int o = rest % CC;
  int k = rest / CC;
  float f = in[(o * CC + i) * K + k];
  u16 h = bf16hi(f);
  hi[idx] = h;
  lo[idx] = bf16hi(f - bf2f(h));
}

__global__ __launch_bounds__(256) void k_wsplit_in(const float* __restrict__ Wf,
    const float* __restrict__ Wft, u16* __restrict__ hi, u16* __restrict__ lo) {
  int idx = blockIdx.x * 256 + threadIdx.x;
  if (idx >= 768 * CC) return;
  int k = idx % CC;
  int j = idx / CC;
  float f = 0.0f;
  if (j < 387) f = Wf[k * 387 + j];
  else if (j < 582) f = Wft[k * 195 + (j - 387)];
  u16 h = bf16hi(f);
  hi[idx] = h;
  lo[idx] = bf16hi(f - bf2f(h));
}

__global__ __launch_bounds__(256) void k_wsplit_d(const float* __restrict__ in,
    u16* __restrict__ hi, u16* __restrict__ lo) {
  int idx = blockIdx.x * 256 + threadIdx.x;
  if (idx >= CC * CC) return;
  float f = in[idx];
  u16 h = bf16hi(f);
  hi[idx] = h;
  lo[idx] = bf16hi(f - bf2f(h));
}

__global__ __launch_bounds__(256) void k_wsplit_t(const float* __restrict__ in,
    u16* __restrict__ hi, u16* __restrict__ lo) {
  int idx = blockIdx.x * 256 + threadIdx.x;
  if (idx >= CC * CC) return;
  int c = idx % CC;
  int o = idx / CC;
  float f = in[c * CC + o];
  u16 h = bf16hi(f);
  hi[idx] = h;
  lo[idx] = bf16hi(f - bf2f(h));
}

// ================= input projection, split-bf16 MFMA =================
__global__ __launch_bounds__(256, 3) void k_in_mfma(const float* __restrict__ x,
    const u16* __restrict__ WIh, const u16* __restrict__ WIl,
    const float* __restrict__ bf, const float* __restrict__ bft,
    float* __restrict__ QS, float* __restrict__ CS, float* __restrict__ GS,
    float* __restrict__ CT, float* __restrict__ GT)
{
  __shared__ __align__(16) u16 xh[32 * 200];
  __shared__ __align__(16) u16 xl[32 * 200];
  const int tid  = threadIdx.x;
  const int lane = tid & 63;
  const int w    = tid >> 6;
  const int lrow = lane & 15;
  const int lk   = (lane >> 4) * 8;
  const int orow = (lane >> 4) * 4;
  const int tk0  = blockIdx.x * 32;
  const int jw0  = blockIdx.y * 320 + w * 80;

  #pragma unroll
  for (int it = 0; it < 6; ++it) {
    int idx = tid + it * 256;                 // 0..1535
    int tokl = idx / 48;
    int c = (idx - tokl * 48) * 4;
    float4 v = *(const float4*)(x + (size_t)(tk0 + tokl) * CC + c);
    split4(v, (uint2*)&xh[tokl * 200 + c], (uint2*)&xl[tokl * 200 + c]);
  }
  __syncthreads();

  f32x4 acc[5][2] = {};
  #pragma unroll
  for (int kb = 0; kb < 6; ++kb) {
    int k0 = kb * 32;
    short8v ah[5], al[5], bh[2], bl[2];
    #pragma unroll
    for (int r = 0; r < 5; ++r) {
      size_t aoff = (size_t)(jw0 + r * 16 + lrow) * 192 + k0 + lk;
      ah[r] = *(const short8v*)(WIh + aoff);
      al[r] = *(const short8v*)(WIl + aoff);
    }
    #pragma unroll
    for (int c = 0; c < 2; ++c) {
      int tokl = c * 16 + lrow;
      bh[c] = *(const short8v*)&xh[tokl * 200 + k0 + lk];
      bl[c] = *(const short8v*)&xl[tokl * 200 + k0 + lk];
    }
    #pragma unroll
    for (int r = 0; r < 5; ++r)
      #pragma unroll
      for (int c = 0; c < 2; ++c) {
        acc[r][c] = __builtin_amdgcn_mfma_f32_16x16x32_bf16(ah[r], bh[c], acc[r][c], 0, 0, 0);
        acc[r][c] = __builtin_amdgcn_mfma_f32_16x16x32_bf16(ah[r], bl[c], acc[r][c], 0, 0, 0);
        acc[r][c] = __builtin_amdgcn_mfma_f32_16x16x32_bf16(al[r], bh[c], acc[r][c], 0, 0, 0);
      }
  }

  #pragma unroll
  for (int c = 0; c < 2; ++c) {
    int tok = tk0 + c * 16 + lrow;
    int bb = tok / PP;
    int hw = tok - bb * PP;
    size_t ctbase = ((size_t)((bb >> 3) * PP + hw) * 8 + (size_t)(bb & 7));
    #pragma unroll
    for (int r = 0; r < 5; ++r) {
      int jb = jw0 + r * 16 + orow;
      #pragma unroll
      for (int u = 0; u < 4; ++u) {
        int j = jb + u;
        if (j >= 582) continue;
        float bias = (j < 387) ? bf[j] : bft[j - 387];
        float val = acc[r][c][u] + bias;
        if (j < 192)      QS[(size_t)tok * CC + j] = val;
        else if (j < 384) CS[(size_t)tok * CC + (j - 192)] = val;
        else if (j < 387) GS[(size_t)tok * 3 + (j - 384)] = val;
        else if (j < 579) CT[ctbase * CC + (j - 387)] = val;
        else              GT[ctbase * 3 + (j - 579)] = val;
      }
    }
  }
}

// ---------------- temporal body (r11/r14 proven 4-seq version) ----------------
#define PADB 200
__device__ __forceinline__ void t_body(char* smem, int tblk,
    const float* __restrict__ CT, const float* __restrict__ GT,
    const u16* __restrict__ W3h, const u16* __restrict__ W5h,
    const u16* __restrict__ WHh, const u16* __restrict__ WHl,
    const float* __restrict__ bht, float* __restrict__ MT)
{
  u16* bufh = (u16*)smem;                       // 48*200 u16 = 19200 B
  u16* bufl = bufh + 48 * PADB;                 // 19200 B
  float* gbuf = (float*)(bufl + 48 * PADB);     // 384 B

  const int tid  = threadIdx.x;
  const int lane = tid & 63;
  const int w    = tid >> 6;
  const int m0   = w * 48;
  const int lrow = lane & 15;
  const int lk   = (lane >> 4) * 8;
  const int orow = (lane >> 4) * 4;
  const int n0   = tblk * 4;

  if (tid < 96) gbuf[tid] = GT[(size_t)n0 * 24 + tid];

  for (int i = tid; i < 16 * 96; i += 256) {
    int hc = i / 96, j = i - hc * 96;
    int s = hc >> 2, which = hc & 3;
    int pc = s * 12 + ((which < 2) ? which : (8 + which));   // 0,1,10,11
    ((unsigned*)&bufh[pc * PADB])[j] = 0u;
    ((unsigned*)&bufl[pc * PADB])[j] = 0u;
  }

  {
    const float4* src = (const float4*)(CT + (size_t)n0 * 1536);
    #pragma unroll
    for (int it = 0; it < 6; ++it) {
      int idx = tid + it * 256;           // 0..1535 float4
      int e = idx * 4;
      int s = e / 1536;
      int r2 = e - s * 1536;
      int t = r2 / 192;
      int c = r2 - t * 192;
      float4 v = src[idx];
      int pc = s * 12 + 2 + t;
      split4(v, (uint2*)&bufh[pc * PADB + c], (uint2*)&bufl[pc * PADB + c]);
    }
  }
  __syncthreads();

  int pcolBase[2];
  #pragma unroll
  for (int c = 0; c < 2; ++c) {
    int col = c * 16 + lrow;
    pcolBase[c] = (col >> 3) * 12 + 2 + (col & 7);
  }

#define LOADA1(WH, OFF, KB, AH) { \
    _Pragma("unroll") for (int r = 0; r < 3; ++r) { \
      size_t aoff = ((size_t)((OFF) * 192 + m0 + r * 16 + lrow)) * 192 + (KB) * 32 + lk; \
      AH[r] = *(const short8v*)(WH + aoff); } }
#define LOADB_T(SH, KB, BH, BL) { \
    _Pragma("unroll") for (int c = 0; c < 2; ++c) { \
      int pc = pcolBase[c] + (SH); \
      BH[c] = *(const short8v*)&bufh[pc * PADB + (KB) * 32 + lk]; \
      BL[c] = *(const short8v*)&bufl[pc * PADB + (KB) * 32 + lk]; } }
#define MFMA4(AH, BH, BL, ACC) { \
    _Pragma("unroll") for (int r = 0; r < 3; ++r) \
      _Pragma("unroll") for (int c = 0; c < 2; ++c) { \
        ACC[r][c] = __builtin_amdgcn_mfma_f32_16x16x32_bf16(AH[r], BH[c], ACC[r][c], 0, 0, 0); \
        ACC[r][c] = __builtin_amdgcn_mfma_f32_16x16x32_bf16(AH[r], BL[c], ACC[r][c], 0, 0, 0); } }

  // ---- conv K=3 ----
  f32x4 acc[3][2] = {};
  #pragma unroll
  for (int off = 0; off < 3; ++off) {
    #pragma unroll
    for (int kb = 0; kb < 6; ++kb) {
      short8v ah[3], bh[2], bl[2];
      LOADA1(W3h, off, kb, ah);
      LOADB_T(off - 1, kb, bh, bl);
      MFMA4(ah, bh, bl, acc);
    }
  }
  __syncthreads();

  // ---- conv3 epilogue: c1 -> buf ----
  #pragma unroll
  for (int r = 0; r < 3; ++r) {
    int o = m0 + r * 16 + orow;
    #pragma unroll
    for (int c = 0; c < 2; ++c) {
      int pc = pcolBase[c];
      f32x4 a = acc[r][c];
      u16 hh[4], ll[4];
      #pragma unroll
      for (int u = 0; u < 4; ++u) {
        float c1v = gelu_f(a[u]);
        hh[u] = bf16hi(c1v);
        ll[u] = bf16hi(c1v - bf2f(hh[u]));
      }
      *(uint2*)&bufh[pc * PADB + o] =
          make_uint2((unsigned)hh[0] | ((unsigned)hh[1] << 16),
                     (unsigned)hh[2] | ((unsigned)hh[3] << 16));
      *(uint2*)&bufl[pc * PADB + o] =
          make_uint2((unsigned)ll[0] | ((unsigned)ll[1] << 16),
                     (unsigned)ll[2] | ((unsigned)ll[3] << 16));
    }
  }
  __syncthreads();

  // ---- conv K=5 ----
  f32x4 acc2[3][2] = {};
  #pragma unroll
  for (int off = 0; off < 5; ++off) {
    #pragma unroll
    for (int kb = 0; kb < 6; ++kb) {
      short8v ah[3], bh[2], bl[2];
      LOADA1(W5h, off, kb, ah);
      LOADB_T(off - 2, kb, bh, bl);
      MFMA4(ah, bh, bl, acc2);
    }
  }
  __syncthreads();

  // ---- conv5 epilogue: ctx_all = c1*g0 + c2*g1 + gm*g2 -> buf ----
  #pragma unroll
  for (int r = 0; r < 3; ++r) {
    int o = m0 + r * 16 + orow;
    #pragma unroll
    for (int c = 0; c < 2; ++c) {
      int col = c * 16 + lrow;
      int pc = pcolBase[c];
      float g0 = gbuf[col * 3 + 0];
      float g1 = gbuf[col * 3 + 1];
      float g2 = gbuf[col * 3 + 2];
      f32x4 a = acc2[r][c];
      uint2 c1hv = *(const uint2*)&bufh[pc * PADB + o];
      uint2 c1lv = *(const uint2*)&bufl[pc * PADB + o];
      u16 c1h4[4] = {(u16)(c1hv.x & 0xffff), (u16)(c1hv.x >> 16),
                     (u16)(c1hv.y & 0xffff), (u16)(c1hv.y >> 16)};
      u16 c1l4[4] = {(u16)(c1lv.x & 0xffff), (u16)(c1lv.x >> 16),
                     (u16)(c1lv.y & 0xffff), (u16)(c1lv.y >> 16)};
      u16 hh[4], ll[4];
      #pragma unroll
      for (int u = 0; u < 4; ++u) {
        float cv = gelu_f(a[u]);
        float sm = cv;
        sm += __shfl_xor(sm, 1);
        sm += __shfl_xor(sm, 2);
        sm += __shfl_xor(sm, 4);
        float gm = gelu_f(sm * 0.125f);
        float c1full = bf2f(c1h4[u]) + bf2f(c1l4[u]);
        float av = c1full * g0 + cv * g1 + gm * g2;
        hh[u] = bf16hi(av);
        ll[u] = bf16hi(av - bf2f(hh[u]));
      }
      *(uint2*)&bufh[pc * PADB + o] =
          make_uint2((unsigned)hh[0] | ((unsigned)hh[1] << 16),
                     (unsigned)hh[2] | ((unsigned)hh[3] << 16));
      *(uint2*)&bufl[pc * PADB + o] =
          make_uint2((unsigned)ll[0] | ((unsigned)ll[1] << 16),
                     (unsigned)ll[2] | ((unsigned)ll[3] << 16));
    }
  }
  __syncthreads();

  // ---- mod_t = Wht @ ctx_all + bht : Wht FULL split ----
  f32x4 acc3[3][2] = {};
  #pragma unroll
  for (int kb = 0; kb < 6; ++kb) {
    short8v ah[3], al[3], bh[2], bl[2];
    #pragma unroll
    for (int r = 0; r < 3; ++r) {
      size_t aoff = ((size_t)(m0 + r * 16 + lrow)) * 192 + kb * 32 + lk;
      ah[r] = *(const short8v*)(WHh + aoff);
      al[r] = *(const short8v*)(WHl + aoff);
    }
    LOADB_T(0, kb, bh, bl);
    #pragma unroll
    for (int r = 0; r < 3; ++r)
      #pragma unroll
      for (int c = 0; c < 2; ++c) {
        acc3[r][c] = __builtin_amdgcn_mfma_f32_16x16x32_bf16(ah[r], bh[c], acc3[r][c], 0, 0, 0);
        acc3[r][c] = __builtin_amdgcn_mfma_f32_16x16x32_bf16(ah[r], bl[c], acc3[r][c], 0, 0, 0);
        acc3[r][c] = __builtin_amdgcn_mfma_f32_16x16x32_bf16(al[r], bh[c], acc3[r][c], 0, 0, 0);
      }
  }
#undef LOADA1
#undef LOADB_T
#undef MFMA4

  // ---- store mod_t in SPATIAL token order ----
  #pragma unroll
  for (int r = 0; r < 3; ++r) {
    int o = m0 + r * 16 + orow;
    float4 bb4 = *(const float4*)&bht[o];
    #pragma unroll
    for (int c = 0; c < 2; ++c) {
      int col = c * 16 + lrow;
      int n = n0 + (col >> 3);
      int t = col & 7;
      int bg = n / PP;
      int hw = n - bg * PP;
      size_t tk = (size_t)(bg * 8 + t) * PP + hw;
      f32x4 a = acc3[r][c];
      *(float4*)&MT[tk * CC + o] =
          make_float4(a[0] + bb4.x, a[1] + bb4.y, a[2] + bb4.z, a[3] + bb4.w);
    }
  }
}

// ---------------- spatial conv body ----------------
__device__ __forceinline__ void dwf_body(char* smem, int tile, int cgi, int bb,
    const float* __restrict__ CTX, const float* __restrict__ GS,
    const float* __restrict__ fw0, const float* __restrict__ fw1,
    float* __restrict__ A0, float* __restrict__ GMpart)
{
  float* sctx  = (float*)smem;            // 6272 f (25088 B)
  float* sc1   = sctx + 6272;             // 4608 f (18432 B)
  float* w3s   = sc1 + 4608;              // 288 f
  float* w5s   = w3s + 288;               // 800 f
  float* smean = w5s + 800;               // 256 f   (total 48896 B)
  const int tid  = threadIdx.x;
  const int ty0  = (tile / 7) * 8;
  const int tx0  = (tile % 7) * 8;
  const int c0   = cgi * 32;

  for (int i = tid; i < 288; i += 256) {
    int k = i / 32, c = i - (i / 32) * 32;
    w3s[k * 32 + c] = fw0[(c0 + c) * 9 + k];
  }
  for (int i = tid; i < 800; i += 256) {
    int k = i / 32, c = i - (i / 32) * 32;
    w5s[k * 32 + c] = fw1[(c0 + c) * 25 + k];
  }

  for (int i = tid; i < 1568; i += 256) {
    int tok = i >> 3;
    int part = i & 7;
    int y = tok / 14, x = tok - y * 14;
    int gh = ty0 + y - 3, gw = tx0 + x - 3;
    float4 v = make_float4(0.f, 0.f, 0.f, 0.f);
    if (gh >= 0 && gh < HH && gw >= 0 && gw < WWD)
      v = *(const float4*)(CTX + ((size_t)bb * PP + gh * WWD + gw) * CC + c0 + part * 4);
    *(float4*)&sctx[tok * 32 + part * 4] = v;
  }
  __syncthreads();

  for (int i = tid; i < 4608; i += 256) {
    int c = i & 31, tok = i >> 5;
    int y = tok / 12, x = tok - y * 12;
    float s = 0.f;
    #pragma unroll
    for (int dy = 0; dy < 3; ++dy)
      #pragma unroll
      for (int dx = 0; dx < 3; ++dx)
        s = fmaf(sctx[((y + dy) * 14 + (x + dx)) * 32 + c], w3s[(dy * 3 + dx) * 32 + c], s);
    sc1[tok * 32 + c] = gelu_f(s);
  }
  __syncthreads();

  float ms = 0.f;
  #pragma unroll
  for (int p = 0; p < 8; ++p) {
    int i = tid + p * 256;
    int c = i & 31, tok = i >> 5;
    int y = tok >> 3, x = tok & 7;
    float s = 0.f;
    #pragma unroll
    for (int dy = 0; dy < 5; ++dy)
      #pragma unroll
      for (int dx = 0; dx < 5; ++dx)
        s = fmaf(sc1[((y + dy) * 12 + (x + dx)) * 32 + c], w5s[(dy * 5 + dx) * 32 + c], s);
    float c2 = gelu_f(s);
    ms += c2;
    float c1v = sc1[((y + 2) * 12 + (x + 2)) * 32 + c];
    size_t tg = (size_t)bb * PP + (size_t)(ty0 + y) * WWD + (tx0 + x);
    float g0 = GS[tg * 3 + 0];
    float g1 = GS[tg * 3 + 1];
    A0[tg * CC + c0 + c] = c1v * g0 + c2 * g1;
  }
  smean[tid] = ms;
  __syncthreads();
  if (tid < 32) {
    float s = 0.f;
    #pragma unroll
    for (int p = 0; p < 8; ++p) s += smean[p * 32 + tid];
    GMpart[(size_t)tile * 6144 + bb * CC + c0 + tid] = s;
  }
}

// ================= standalone wrappers (fallback path) =================
__global__ __launch_bounds__(256, 3) void k_t_mfma(
    const float* __restrict__ CT, const float* __restrict__ GT,
    const u16* __restrict__ W3h, const u16* __restrict__ W5h,
    const u16* __restrict__ WHh, const u16* __restrict__ WHl,
    const float* __restrict__ bht, float* __restrict__ MT)
{
  __shared__ __align__(16) char smem[48896];
  t_body(smem, blockIdx.x, CT, GT, W3h, W5h, WHh, WHl, bht, MT);
}

__global__ __launch_bounds__(256) void k_dwf(const float* __restrict__ CTX,
    const float* __restrict__ GS, const float* __restrict__ fw0,
    const float* __restrict__ fw1, float* __restrict__ A0,
    float* __restrict__ GMpart)
{
  __shared__ __align__(16) char smem[48896];
  dwf_body(smem, blockIdx.x, blockIdx.y, blockIdx.z, CTX, GS, fw0, fw1, A0, GMpart);
}

// ================= fused heterogeneous kernel (concurrent path) =================
// bid%4==0 -> temporal block (3136 of 12544); else spatial (9408). 1:3 interleave
// keeps MFMA/L2-bound temporal waves and VALU/LDS-bound spatial waves co-resident
// on every CU (m114: separate pipes overlap at ~max, not sum).
__global__ __launch_bounds__(256, 3) void k_fused(
    const float* __restrict__ CT, const float* __restrict__ GT,
    const u16* __restrict__ W3h, const u16* __restrict__ W5h,
    const u16* __restrict__ WHh, const u16* __restrict__ WHl,
    const float* __restrict__ bht, float* __restrict__ MT,
    const float* __restrict__ CTX, const float* __restrict__ GS,
    const float* __restrict__ fw0, const float* __restrict__ fw1,
    float* __restrict__ A0, float* __restrict__ GMpart)
{
  __shared__ __align__(16) char smem[48896];
  const int bid = blockIdx.x;
  if ((bid & 3) == 0) {
    t_body(smem, bid >> 2, CT, GT, W3h, W5h, WHh, WHl, bht, MT);
  } else {
    int s = bid - (bid >> 2) - 1;         // 0..9407
    int tile = s % 49;
    int rest = s / 49;
    int cgi = rest % 6;
    int bb = rest / 6;
    dwf_body(smem, tile, cgi, bb, CTX, GS, fw0, fw1, A0, GMpart);
  }
}

__global__ __launch_bounds__(256) void k_gmg(const float* __restrict__ GMpart,
                                             float* __restrict__ GMg)
{
  int i = blockIdx.x * 256 + threadIdx.x;
  if (i >= 6144) return;
  float s = 0.f;
  for (int p = 0; p < 49; ++p) s += GMpart[(size_t)p * 6144 + i];
  GMg[i] = gelu_f(s * (1.0f / 3136.0f));
}

// ================= fused mod+out GEMM =================
__global__ __launch_bounds__(256, 3) void k_modout(float* __restrict__ A0,
    const float* __restrict__ GS, const float* __restrict__ GMg,
    const u16* __restrict__ Wmh, const u16* __restrict__ Wml,
    const float* __restrict__ bh, const float* __restrict__ QS,
    float* MTout, const u16* __restrict__ Wph, const u16* __restrict__ Wpl,
    const float* __restrict__ bp)
{
  __shared__ __align__(16) u16 sh_[32 * 200];
  __shared__ __align__(16) u16 sl_[32 * 200];
  const int tid  = threadIdx.x;
  const int lane = tid & 63;
  const int w    = tid >> 6;
  const int lrow = lane & 15;
  const int lk   = (lane >> 4) * 8;
  const int orow = (lane >> 4) * 4;
  const int tk0  = blockIdx.x * 32;
  const int m0   = w * 48;

  // ---- stage phase-1 A operand: A0 + gm*g2 ----
  #pragma unroll
  for (int it = 0; it < 6; ++it) {
    int idx = tid + it * 256;
    int tokl = idx / 48;
    int c = (idx - tokl * 48) * 4;
    int tok = tk0 + tokl;
    int bb = tok / PP;
    size_t base = (size_t)tok * CC + c;
    float4 v1 = *(const float4*)(A0 + base);
    float4 vg = *(const float4*)(GMg + bb * CC + c);
    float g2 = GS[(size_t)tok * 3 + 2];
    float4 av = make_float4(v1.x + vg.x * g2, v1.y + vg.y * g2,
                            v1.z + vg.z * g2, v1.w + vg.w * g2);
    split4(av, (uint2*)&sh_[tokl * 200 + c], (uint2*)&sl_[tokl * 200 + c]);
  }
  __syncthreads();

#define LOADA_G(WH, WL, KB, AH, AL) { \
    _Pragma("unroll") for (int r = 0; r < 3; ++r) { \
      size_t aoff = (size_t)(m0 + r * 16 + lrow) * 192 + (KB) * 32 + lk; \
      AH[r] = *(const short8v*)(WH + aoff); \
      AL[r] = *(const short8v*)(WL + aoff); } }
#define LOADB_G(KB, BH, BL) { \
    _Pragma("unroll") for (int c = 0; c < 2; ++c) { \
      int tokl = c * 16 + lrow; \
      BH[c] = *(const short8v*)&sh_[tokl * 200 + (KB) * 32 + lk]; \
      BL[c] = *(const short8v*)&sl_[tokl * 200 + (KB) * 32 + lk]; } }
#define GEMM6(WH, WL, ACC) { \
    _Pragma("unroll") for (int kb = 0; kb < 6; ++kb) { \
      short8v ah[3], al[3], bh4[2], bl4[2]; \
      LOADA_G(WH, WL, kb, ah, al); \
      LOADB_G(kb, bh4, bl4); \
      _Pragma("unroll") for (int r = 0; r < 3; ++r) \
        _Pragma("unroll") for (int c = 0; c < 2; ++c) { \
          ACC[r][c] = __builtin_amdgcn_mfma_f32_16x16x32_bf16(ah[r], bh4[c], ACC[r][c], 0, 0, 0); \
          ACC[r][c] = __builtin_amdgcn_mfma_f32_16x16x32_bf16(ah[r], bl4[c], ACC[r][c], 0, 0, 0); \
          ACC[r][c] = __builtin_amdgcn_mfma_f32_16x16x32_bf16(al[r], bh4[c], ACC[r][c], 0, 0, 0); } } }

  // ---- phase 1 GEMM: MOD ----
  f32x4 acc[3][2] = {};
  GEMM6(Wmh, Wml, acc);
  __syncthreads();   // all phase-1 B reads done before MOD overwrites LDS

  // ---- write MOD (+bh) hi/lo into LDS ----
  #pragma unroll
  for (int r = 0; r < 3; ++r) {
    int jb = m0 + r * 16 + orow;
    float4 b4 = *(const float4*)&bh[jb];
    #pragma unroll
    for (int c = 0; c < 2; ++c) {
      int tokl = c * 16 + lrow;
      f32x4 a = acc[r][c];
      float4 mv = make_float4(a[0] + b4.x, a[1] + b4.y, a[2] + b4.z, a[3] + b4.w);
      split4(mv, (uint2*)&sh_[tokl * 200 + jb], (uint2*)&sl_[tokl * 200 + jb]);
    }
  }
  __syncthreads();

  // ---- restage: A2 = q * MOD * mod_t (own-slot read-then-write) ----
  #pragma unroll
  for (int it = 0; it < 6; ++it) {
    int idx = tid + it * 256;
    int tokl = idx / 48;
    int c = (idx - tokl * 48) * 4;
    size_t base = (size_t)(tk0 + tokl) * CC + c;
    float4 q  = *(const float4*)(QS + base);
    float4 mt = *(const float4*)(MTout + base);
    uint2 mh = *(const uint2*)&sh_[tokl * 200 + c];
    uint2 ml = *(const uint2*)&sl_[tokl * 200 + c];
    float m0v = bf2f((u16)(mh.x & 0xffff)) + bf2f((u16)(ml.x & 0xffff));
    float m1v = bf2f((u16)(mh.x >> 16))    + bf2f((u16)(ml.x >> 16));
    float m2v = bf2f((u16)(mh.y & 0xffff)) + bf2f((u16)(ml.y & 0xffff));
    float m3v = bf2f((u16)(mh.y >> 16))    + bf2f((u16)(ml.y >> 16));
    float4 av = make_float4(q.x * m0v * mt.x, q.y * m1v * mt.y,
                            q.z * m2v * mt.z, q.w * m3v * mt.w);
    split4(av, (uint2*)&sh_[tokl * 200 + c], (uint2*)&sl_[tokl * 200 + c]);
  }
  __syncthreads();

  // ---- phase 2 GEMM: out ----
  f32x4 acc2[3][2] = {};
  GEMM6(Wph, Wpl, acc2);
#undef LOADA_G
#undef LOADB_G
#undef GEMM6

  // ---- write out over MT in-place ----
  #pragma unroll
  for (int r = 0; r < 3; ++r) {
    int jb = m0 + r * 16 + orow;
    float4 b4 = *(const float4*)&bp[jb];
    #pragma unroll
    for (int c = 0; c < 2; ++c) {
      int tok = tk0 + c * 16 + lrow;
      f32x4 a = acc2[r][c];
      *(float4*)&MTout[(size_t)tok * CC + jb] =
          make_float4(a[0] + b4.x, a[1] + b4.y, a[2] + b4.z, a[3] + b4.w);
    }
  }
}

extern "C" void kernel_launch(void* const* d_in, const int* in_sizes, int n_in,
                              void* d_out, int out_size, void* d_ws, size_t ws_size,
                              hipStream_t stream)
{
  (void)in_sizes; (void)n_in; (void)out_size;
  const float* x   = (const float*)d_in[0];
  const float* Wf  = (const float*)d_in[1];
  const float* bf  = (const float*)d_in[2];
  const float* Wft = (const float*)d_in[3];
  const float* bft = (const float*)d_in[4];
  const float* fw0 = (const float*)d_in[5];
  const float* fw1 = (const float*)d_in[6];
  const float* tw0 = (const float*)d_in[7];
  const float* tw1 = (const float*)d_in[8];
  const float* Wh  = (const float*)d_in[9];
  const float* bh  = (const float*)d_in[10];
  const float* Wht = (const float*)d_in[11];
  const float* bht = (const float*)d_in[12];
  const float* Wp  = (const float*)d_in[13];
  const float* bp  = (const float*)d_in[14];

  float* ws = (float*)d_ws;
  const size_t SZ = (size_t)NTOK * CC;          // 19,267,584 floats (77 MB)
  float* QS     = ws + 0 * SZ;                  // q (spatial)
  float* WS1    = ws + 1 * SZ;                  // ctx_s
  float* WS2    = ws + 2 * SZ;                  // ctx_t (and A0 in fallback)
  float* MT     = (float*)d_out;                // mod_t (spatial order) -> out, in-place
  float* GS     = ws + 3 * SZ;                  // gates_s [tok][3]
  float* GT     = GS + (size_t)NTOK * 3;        // gates_t [n*8+t][3]
  float* GMpart = GT + (size_t)NTOK * 3;        // 49 x 6144
  float* GMg    = GMpart + 49 * 6144;           // gelu(mean) [32][192]
  u16* W3h = (u16*)(GMg + 6144);                // conv3 [k][o][i] hi
  u16* W3l = W3h + 3 * 36864;
  u16* W5h = W3l + 3 * 36864;
  u16* W5l = W5h + 5 * 36864;
  u16* WHh = W5l + 5 * 36864;
  u16* WHl = WHh + 36864;
  u16* WIh = WHl + 36864;                       // input proj [j<768][k]
  u16* WIl = WIh + 768 * 192;
  u16* Wmh = WIl + 768 * 192;                   // Wh [o][c]
  u16* Wml = Wmh + 36864;
  u16* Wph = Wml + 36864;                       // Wp^T [o][c]
  u16* Wpl = Wph + 36864;
  float* WS3 = (float*)(Wpl + 36864);           // A0 for concurrent path (+77 MB)
  size_t need_bytes = (size_t)((char*)(WS3 + SZ) - (char*)d_ws);
  const bool fused_ok = (ws_size >= need_bytes);

  k_wsplit<<<432, 256, 0, stream>>>(tw0, W3h, W3l, 3);
  k_wsplit<<<720, 256, 0, stream>>>(tw1, W5h, W5l, 5);
  k_wsplit<<<144, 256, 0, stream>>>(Wht, WHh, WHl, 1);
  k_wsplit_in<<<576, 256, 0, stream>>>(Wf, Wft, WIh, WIl);
  k_wsplit_d<<<144, 256, 0, stream>>>(Wh, Wmh, Wml);
  k_wsplit_t<<<144, 256, 0, stream>>>(Wp, Wph, Wpl);

  k_in_mfma<<<dim3(3136, 2), 256, 0, stream>>>(x, WIh, WIl, bf, bft,
                                               QS, WS1, GS, WS2, GT);

  if (fused_ok) {
    // temporal (reads WS2, writes MT) and spatial (reads WS1, writes WS3+GMpart)
    // are disjoint -> run concurrently in one heterogeneous kernel.
    k_fused<<<12544, 256, 0, stream>>>(WS2, GT, W3h, W5h, WHh, WHl, bht, MT,
                                       WS1, GS, fw0, fw1, WS3, GMpart);
    k_gmg<<<24, 256, 0, stream>>>(GMpart, GMg);
    k_modout<<<3136, 256, 0, stream>>>(WS3, GS, GMg, Wmh, Wml, bh,
                                       QS, MT, Wph, Wpl, bp);
  } else {
    k_t_mfma<<<3136, 256, 0, stream>>>(WS2, GT, W3h, W5h, WHh, WHl, bht, MT);
    k_dwf<<<dim3(49, 6, 32), 256, 0, stream>>>(WS1, GS, fw0, fw1, WS2, GMpart);
    k_gmg<<<24, 256, 0, stream>>>(GMpart, GMg);
    k_modout<<<3136, 256, 0, stream>>>(WS2, GS, GMg, Wmh, Wml, bh,
                                       QS, MT, Wph, Wpl, bp);
  }
}

// Round 16
// 966.483 us; speedup vs baseline: 1.0311x; 1.0311x over previous
//
#include <hip/hip_runtime.h>
#include <math.h>

#define CC    192
#define TT    8
#define HH    56
#define WWD   56
#define PP    3136      // H*W
#define NTOK  100352    // 32*56*56
#define NSEQ  12544     // 4*56*56

typedef __attribute__((ext_vector_type(8))) short short8v;  // 8 bf16 (4 VGPR)
typedef __attribute__((ext_vector_type(4))) float f32x4;
using u16 = unsigned short;

__device__ __forceinline__ float gelu_f(float v) {
  return 0.5f * v * (1.0f + erff(v * 0.70710678f));
}

__device__ __forceinline__ u16 bf16hi(float f) {
  unsigned u = __builtin_bit_cast(unsigned, f);
  u += 0x7fffu + ((u >> 16) & 1u);
  return (u16)(u >> 16);
}
__device__ __forceinline__ float bf2f(u16 h) {
  unsigned u = ((unsigned)h) << 16;
  return __builtin_bit_cast(float, u);
}

__device__ __forceinline__ void split4(float4 v, uint2* ph, uint2* pl) {
  float vv[4] = {v.x, v.y, v.z, v.w};
  u16 hh[4], ll[4];
  #pragma unroll
  for (int u = 0; u < 4; ++u) {
    hh[u] = bf16hi(vv[u]);
    ll[u] = bf16hi(vv[u] - bf2f(hh[u]));
  }
  *ph = make_uint2((unsigned)hh[0] | ((unsigned)hh[1] << 16),
                   (unsigned)hh[2] | ((unsigned)hh[3] << 16));
  *pl = make_uint2((unsigned)ll[0] | ((unsigned)ll[1] << 16),
                   (unsigned)ll[2] | ((unsigned)ll[3] << 16));
}

// ---------------- weight split kernels ----------------
__global__ __launch_bounds__(256) void k_wsplit(const float* __restrict__ in,
    u16* __restrict__ hi, u16* __restrict__ lo, int K) {
  int idx = blockIdx.x * 256 + threadIdx.x;
  int total = CC * CC * K;
  if (idx >= total) return;
  int i = idx % CC;
  int rest = idx / CC;
  int o = rest % CC;
  int k = rest / CC;
  float f = in[(o * CC + i) * K + k];
  u16 h = bf16hi(f);
  hi[idx] = h;
  lo[idx] = bf16hi(f - bf2f(h));
}

__global__ __launch_bounds__(256) void k_wsplit_in(const float* __restrict__ Wf,
    const float* __restrict__ Wft, u16* __restrict__ hi, u16* __restrict__ lo) {
  int idx = blockIdx.x * 256 + threadIdx.x;
  if (idx >= 768 * CC) return;
  int k = idx % CC;
  int j = idx / CC;
  float f = 0.0f;
  if (j < 387) f = Wf[k * 387 + j];
  else if (j < 582) f = Wft[k * 195 + (j - 387)];
  u16 h = bf16hi(f);
  hi[idx] = h;
  lo[idx] = bf16hi(f - bf2f(h));
}

__global__ __launch_bounds__(256) void k_wsplit_d(const float* __restrict__ in,
    u16* __restrict__ hi, u16* __restrict__ lo) {
  int idx = blockIdx.x * 256 + threadIdx.x;
  if (idx >= CC * CC) return;
  float f = in[idx];
  u16 h = bf16hi(f);
  hi[idx] = h;
  lo[idx] = bf16hi(f - bf2f(h));
}

__global__ __launch_bounds__(256) void k_wsplit_t(const float* __restrict__ in,
    u16* __restrict__ hi, u16* __restrict__ lo) {
  int idx = blockIdx.x * 256 + threadIdx.x;
  if (idx >= CC * CC) return;
  int c = idx % CC;
  int o = idx / CC;
  float f = in[c * CC + o];
  u16 h = bf16hi(f);
  hi[idx] = h;
  lo[idx] = bf16hi(f - bf2f(h));
}

// ================= input projection, split-bf16 MFMA =================
__global__ __launch_bounds__(256, 3) void k_in_mfma(const float* __restrict__ x,
    const u16* __restrict__ WIh, const u16* __restrict__ WIl,
    const float* __restrict__ bf, const float* __restrict__ bft,
    float* __restrict__ QS, float* __restrict__ CS, float* __restrict__ GS,
    float* __restrict__ CT, float* __restrict__ GT)
{
  __shared__ __align__(16) u16 xh[32 * 200];
  __shared__ __align__(16) u16 xl[32 * 200];
  const int tid  = threadIdx.x;
  const int lane = tid & 63;
  const int w    = tid >> 6;
  const int lrow = lane & 15;
  const int lk   = (lane >> 4) * 8;
  const int orow = (lane >> 4) * 4;
  const int tk0  = blockIdx.x * 32;
  const int jw0  = blockIdx.y * 320 + w * 80;

  #pragma unroll
  for (int it = 0; it < 6; ++it) {
    int idx = tid + it * 256;                 // 0..1535
    int tokl = idx / 48;
    int c = (idx - tokl * 48) * 4;
    float4 v = *(const float4*)(x + (size_t)(tk0 + tokl) * CC + c);
    split4(v, (uint2*)&xh[tokl * 200 + c], (uint2*)&xl[tokl * 200 + c]);
  }
  __syncthreads();

  f32x4 acc[5][2] = {};
  #pragma unroll
  for (int kb = 0; kb < 6; ++kb) {
    int k0 = kb * 32;
    short8v ah[5], al[5], bh[2], bl[2];
    #pragma unroll
    for (int r = 0; r < 5; ++r) {
      size_t aoff = (size_t)(jw0 + r * 16 + lrow) * 192 + k0 + lk;
      ah[r] = *(const short8v*)(WIh + aoff);
      al[r] = *(const short8v*)(WIl + aoff);
    }
    #pragma unroll
    for (int c = 0; c < 2; ++c) {
      int tokl = c * 16 + lrow;
      bh[c] = *(const short8v*)&xh[tokl * 200 + k0 + lk];
      bl[c] = *(const short8v*)&xl[tokl * 200 + k0 + lk];
    }
    #pragma unroll
    for (int r = 0; r < 5; ++r)
      #pragma unroll
      for (int c = 0; c < 2; ++c) {
        acc[r][c] = __builtin_amdgcn_mfma_f32_16x16x32_bf16(ah[r], bh[c], acc[r][c], 0, 0, 0);
        acc[r][c] = __builtin_amdgcn_mfma_f32_16x16x32_bf16(ah[r], bl[c], acc[r][c], 0, 0, 0);
        acc[r][c] = __builtin_amdgcn_mfma_f32_16x16x32_bf16(al[r], bh[c], acc[r][c], 0, 0, 0);
      }
  }

  #pragma unroll
  for (int c = 0; c < 2; ++c) {
    int tok = tk0 + c * 16 + lrow;
    int bb = tok / PP;
    int hw = tok - bb * PP;
    size_t ctbase = ((size_t)((bb >> 3) * PP + hw) * 8 + (size_t)(bb & 7));
    #pragma unroll
    for (int r = 0; r < 5; ++r) {
      int jb = jw0 + r * 16 + orow;
      #pragma unroll
      for (int u = 0; u < 4; ++u) {
        int j = jb + u;
        if (j >= 582) continue;
        float bias = (j < 387) ? bf[j] : bft[j - 387];
        float val = acc[r][c][u] + bias;
        if (j < 192)      QS[(size_t)tok * CC + j] = val;
        else if (j < 384) CS[(size_t)tok * CC + (j - 192)] = val;
        else if (j < 387) GS[(size_t)tok * 3 + (j - 384)] = val;
        else if (j < 579) CT[ctbase * CC + (j - 387)] = val;
        else              GT[ctbase * 3 + (j - 579)] = val;
      }
    }
  }
}

// ================= temporal pipeline: r11's proven 4-seq version =================
// 4 seq/block, wave owns 48 rows x 2 coltiles; bf16 conv weights + split activations.
// Measured r11/r14: 373 us, occ 31%, VGPR 84 — fastest of all structure/occupancy
// variants tested (2-seq: 558; (256,4) variants spill; full-split: 592; union-smem
// wrapper r15: 391).
#define PADB 200
__global__ __launch_bounds__(256, 3) void k_t_mfma(
    const float* __restrict__ CT, const float* __restrict__ GT,
    const u16* __restrict__ W3h,
    const u16* __restrict__ W5h,
    const u16* __restrict__ WHh, const u16* __restrict__ WHl,
    const float* __restrict__ bht, float* __restrict__ MT)
{
  __shared__ __align__(16) u16 bufh[48 * PADB];
  __shared__ __align__(16) u16 bufl[48 * PADB];
  __shared__ float gbuf[96];

  const int tid  = threadIdx.x;
  const int lane = tid & 63;
  const int w    = tid >> 6;
  const int m0   = w * 48;
  const int lrow = lane & 15;
  const int lk   = (lane >> 4) * 8;
  const int orow = (lane >> 4) * 4;
  const int n0   = blockIdx.x * 4;

  if (tid < 96) gbuf[tid] = GT[(size_t)n0 * 24 + tid];

  // zero halo cols (p%12 in {0,1,10,11})
  for (int i = tid; i < 16 * 96; i += 256) {
    int hc = i / 96, j = i - hc * 96;
    int s = hc >> 2, which = hc & 3;
    int pc = s * 12 + ((which < 2) ? which : (8 + which));   // 0,1,10,11
    ((unsigned*)&bufh[pc * PADB])[j] = 0u;
    ((unsigned*)&bufl[pc * PADB])[j] = 0u;
  }

  // stage ctx: 4 seq * 8 t * 192 c fp32 -> bf16 hi/lo
  {
    const float4* src = (const float4*)(CT + (size_t)n0 * 1536);
    #pragma unroll
    for (int it = 0; it < 6; ++it) {
      int idx = tid + it * 256;           // 0..1535 float4
      int e = idx * 4;
      int s = e / 1536;
      int r2 = e - s * 1536;
      int t = r2 / 192;
      int c = r2 - t * 192;
      float4 v = src[idx];
      int pc = s * 12 + 2 + t;
      split4(v, (uint2*)&bufh[pc * PADB + c], (uint2*)&bufl[pc * PADB + c]);
    }
  }
  __syncthreads();

  int pcolBase[2];
  #pragma unroll
  for (int c = 0; c < 2; ++c) {
    int col = c * 16 + lrow;
    pcolBase[c] = (col >> 3) * 12 + 2 + (col & 7);
  }

#define LOADA1(WH, OFF, KB, AH) { \
    _Pragma("unroll") for (int r = 0; r < 3; ++r) { \
      size_t aoff = ((size_t)((OFF) * 192 + m0 + r * 16 + lrow)) * 192 + (KB) * 32 + lk; \
      AH[r] = *(const short8v*)(WH + aoff); } }
#define LOADB_T(SH, KB, BH, BL) { \
    _Pragma("unroll") for (int c = 0; c < 2; ++c) { \
      int pc = pcolBase[c] + (SH); \
      BH[c] = *(const short8v*)&bufh[pc * PADB + (KB) * 32 + lk]; \
      BL[c] = *(const short8v*)&bufl[pc * PADB + (KB) * 32 + lk]; } }
#define MFMA4(AH, BH, BL, ACC) { \
    _Pragma("unroll") for (int r = 0; r < 3; ++r) \
      _Pragma("unroll") for (int c = 0; c < 2; ++c) { \
        ACC[r][c] = __builtin_amdgcn_mfma_f32_16x16x32_bf16(AH[r], BH[c], ACC[r][c], 0, 0, 0); \
        ACC[r][c] = __builtin_amdgcn_mfma_f32_16x16x32_bf16(AH[r], BL[c], ACC[r][c], 0, 0, 0); } }

  // ---- conv K=3 ----
  f32x4 acc[3][2] = {};
  #pragma unroll
  for (int off = 0; off < 3; ++off) {
    #pragma unroll
    for (int kb = 0; kb < 6; ++kb) {
      short8v ah[3], bh[2], bl[2];
      LOADA1(W3h, off, kb, ah);
      LOADB_T(off - 1, kb, bh, bl);
      MFMA4(ah, bh, bl, acc);
    }
  }
  __syncthreads();

  // ---- conv3 epilogue: c1 -> buf ----
  #pragma unroll
  for (int r = 0; r < 3; ++r) {
    int o = m0 + r * 16 + orow;
    #pragma unroll
    for (int c = 0; c < 2; ++c) {
      int pc = pcolBase[c];
      f32x4 a = acc[r][c];
      u16 hh[4], ll[4];
      #pragma unroll
      for (int u = 0; u < 4; ++u) {
        float c1v = gelu_f(a[u]);
        hh[u] = bf16hi(c1v);
        ll[u] = bf16hi(c1v - bf2f(hh[u]));
      }
      *(uint2*)&bufh[pc * PADB + o] =
          make_uint2((unsigned)hh[0] | ((unsigned)hh[1] << 16),
                     (unsigned)hh[2] | ((unsigned)hh[3] << 16));
      *(uint2*)&bufl[pc * PADB + o] =
          make_uint2((unsigned)ll[0] | ((unsigned)ll[1] << 16),
                     (unsigned)ll[2] | ((unsigned)ll[3] << 16));
    }
  }
  __syncthreads();

  // ---- conv K=5 ----
  f32x4 acc2[3][2] = {};
  #pragma unroll
  for (int off = 0; off < 5; ++off) {
    #pragma unroll
    for (int kb = 0; kb < 6; ++kb) {
      short8v ah[3], bh[2], bl[2];
      LOADA1(W5h, off, kb, ah);
      LOADB_T(off - 2, kb, bh, bl);
      MFMA4(ah, bh, bl, acc2);
    }
  }
  __syncthreads();

  // ---- conv5 epilogue: read own c1 slot; ctx_all = c1*g0 + c2*g1 + gm*g2 -> buf ----
  #pragma unroll
  for (int r = 0; r < 3; ++r) {
    int o = m0 + r * 16 + orow;
    #pragma unroll
    for (int c = 0; c < 2; ++c) {
      int col = c * 16 + lrow;
      int pc = pcolBase[c];
      float g0 = gbuf[col * 3 + 0];
      float g1 = gbuf[col * 3 + 1];
      float g2 = gbuf[col * 3 + 2];
      f32x4 a = acc2[r][c];
      uint2 c1hv = *(const uint2*)&bufh[pc * PADB + o];
      uint2 c1lv = *(const uint2*)&bufl[pc * PADB + o];
      u16 c1h4[4] = {(u16)(c1hv.x & 0xffff), (u16)(c1hv.x >> 16),
                     (u16)(c1hv.y & 0xffff), (u16)(c1hv.y >> 16)};
      u16 c1l4[4] = {(u16)(c1lv.x & 0xffff), (u16)(c1lv.x >> 16),
                     (u16)(c1lv.y & 0xffff), (u16)(c1lv.y >> 16)};
      u16 hh[4], ll[4];
      #pragma unroll
      for (int u = 0; u < 4; ++u) {
        float cv = gelu_f(a[u]);
        float sm = cv;
        sm += __shfl_xor(sm, 1);
        sm += __shfl_xor(sm, 2);
        sm += __shfl_xor(sm, 4);
        float gm = gelu_f(sm * 0.125f);
        float c1full = bf2f(c1h4[u]) + bf2f(c1l4[u]);
        float av = c1full * g0 + cv * g1 + gm * g2;
        hh[u] = bf16hi(av);
        ll[u] = bf16hi(av - bf2f(hh[u]));
      }
      *(uint2*)&bufh[pc * PADB + o] =
          make_uint2((unsigned)hh[0] | ((unsigned)hh[1] << 16),
                     (unsigned)hh[2] | ((unsigned)hh[3] << 16));
      *(uint2*)&bufl[pc * PADB + o] =
          make_uint2((unsigned)ll[0] | ((unsigned)ll[1] << 16),
                     (unsigned)ll[2] | ((unsigned)ll[3] << 16));
    }
  }
  __syncthreads();

  // ---- mod_t = Wht @ ctx_all + bht : Wht FULL split ----
  f32x4 acc3[3][2] = {};
  #pragma unroll
  for (int kb = 0; kb < 6; ++kb) {
    short8v ah[3], al[3], bh[2], bl[2];
    #pragma unroll
    for (int r = 0; r < 3; ++r) {
      size_t aoff = ((size_t)(m0 + r * 16 + lrow)) * 192 + kb * 32 + lk;
      ah[r] = *(const short8v*)(WHh + aoff);
      al[r] = *(const short8v*)(WHl + aoff);
    }
    LOADB_T(0, kb, bh, bl);
    #pragma unroll
    for (int r = 0; r < 3; ++r)
      #pragma unroll
      for (int c = 0; c < 2; ++c) {
        acc3[r][c] = __builtin_amdgcn_mfma_f32_16x16x32_bf16(ah[r], bh[c], acc3[r][c], 0, 0, 0);
        acc3[r][c] = __builtin_amdgcn_mfma_f32_16x16x32_bf16(ah[r], bl[c], acc3[r][c], 0, 0, 0);
        acc3[r][c] = __builtin_amdgcn_mfma_f32_16x16x32_bf16(al[r], bh[c], acc3[r][c], 0, 0, 0);
      }
  }
#undef LOADA1
#undef LOADB_T
#undef MFMA4

  // ---- store mod_t in SPATIAL token order ----
  #pragma unroll
  for (int r = 0; r < 3; ++r) {
    int o = m0 + r * 16 + orow;
    float4 bb4 = *(const float4*)&bht[o];
    #pragma unroll
    for (int c = 0; c < 2; ++c) {
      int col = c * 16 + lrow;
      int n = n0 + (col >> 3);
      int t = col & 7;
      int bg = n / PP;
      int hw = n - bg * PP;
      size_t tk = (size_t)(bg * 8 + t) * PP + hw;
      f32x4 a = acc3[r][c];
      *(float4*)&MT[tk * CC + o] =
          make_float4(a[0] + bb4.x, a[1] + bb4.y, a[2] + bb4.z, a[3] + bb4.w);
    }
  }
}

// ================= fused spatial conv =================
__global__ __launch_bounds__(256) void k_dwf(const float* __restrict__ CTX,
    const float* __restrict__ GS, const float* __restrict__ fw0,
    const float* __restrict__ fw1, float* __restrict__ A0,
    float* __restrict__ GMpart)
{
  __shared__ __align__(16) float sctx[14 * 14 * 32];
  __shared__ __align__(16) float sc1[12 * 12 * 32];
  __shared__ float w3s[9 * 32];
  __shared__ float w5s[25 * 32];
  __shared__ float smean[256];
  const int tid  = threadIdx.x;
  const int tile = blockIdx.x;       // 0..48
  const int cgi  = blockIdx.y;       // 0..5
  const int bb   = blockIdx.z;       // 0..31
  const int ty0  = (tile / 7) * 8;
  const int tx0  = (tile % 7) * 8;
  const int c0   = cgi * 32;

  for (int i = tid; i < 288; i += 256) {
    int k = i / 32, c = i - (i / 32) * 32;
    w3s[k * 32 + c] = fw0[(c0 + c) * 9 + k];
  }
  for (int i = tid; i < 800; i += 256) {
    int k = i / 32, c = i - (i / 32) * 32;
    w5s[k * 32 + c] = fw1[(c0 + c) * 25 + k];
  }

  for (int i = tid; i < 1568; i += 256) {
    int tok = i >> 3;
    int part = i & 7;
    int y = tok / 14, x = tok - y * 14;
    int gh = ty0 + y - 3, gw = tx0 + x - 3;
    float4 v = make_float4(0.f, 0.f, 0.f, 0.f);
    if (gh >= 0 && gh < HH && gw >= 0 && gw < WWD)
      v = *(const float4*)(CTX + ((size_t)bb * PP + gh * WWD + gw) * CC + c0 + part * 4);
    *(float4*)&sctx[tok * 32 + part * 4] = v;
  }
  __syncthreads();

  for (int i = tid; i < 4608; i += 256) {
    int c = i & 31, tok = i >> 5;
    int y = tok / 12, x = tok - y * 12;
    float s = 0.f;
    #pragma unroll
    for (int dy = 0; dy < 3; ++dy)
      #pragma unroll
      for (int dx = 0; dx < 3; ++dx)
        s = fmaf(sctx[((y + dy) * 14 + (x + dx)) * 32 + c], w3s[(dy * 3 + dx) * 32 + c], s);
    sc1[tok * 32 + c] = gelu_f(s);
  }
  __syncthreads();

  float ms = 0.f;
  #pragma unroll
  for (int p = 0; p < 8; ++p) {
    int i = tid + p * 256;
    int c = i & 31, tok = i >> 5;
    int y = tok >> 3, x = tok & 7;
    float s = 0.f;
    #pragma unroll
    for (int dy = 0; dy < 5; ++dy)
      #pragma unroll
      for (int dx = 0; dx < 5; ++dx)
        s = fmaf(sc1[((y + dy) * 12 + (x + dx)) * 32 + c], w5s[(dy * 5 + dx) * 32 + c], s);
    float c2 = gelu_f(s);
    ms += c2;
    float c1v = sc1[((y + 2) * 12 + (x + 2)) * 32 + c];
    size_t tg = (size_t)bb * PP + (size_t)(ty0 + y) * WWD + (tx0 + x);
    float g0 = GS[tg * 3 + 0];
    float g1 = GS[tg * 3 + 1];
    A0[tg * CC + c0 + c] = c1v * g0 + c2 * g1;
  }
  smean[tid] = ms;
  __syncthreads();
  if (tid < 32) {
    float s = 0.f;
    #pragma unroll
    for (int p = 0; p < 8; ++p) s += smean[p * 32 + tid];
    GMpart[(size_t)tile * 6144 + bb * CC + c0 + tid] = s;
  }
}

__global__ __launch_bounds__(256) void k_gmg(const float* __restrict__ GMpart,
                                             float* __restrict__ GMg)
{
  int i = blockIdx.x * 256 + threadIdx.x;
  if (i >= 6144) return;
  float s = 0.f;
  for (int p = 0; p < 49; ++p) s += GMpart[(size_t)p * 6144 + i];
  GMg[i] = gelu_f(s * (1.0f / 3136.0f));
}

// ================= fused mod+out GEMM =================
__global__ __launch_bounds__(256, 3) void k_modout(float* __restrict__ A0,
    const float* __restrict__ GS, const float* __restrict__ GMg,
    const u16* __restrict__ Wmh, const u16* __restrict__ Wml,
    const float* __restrict__ bh, const float* __restrict__ QS,
    float* MTout, const u16* __restrict__ Wph, const u16* __restrict__ Wpl,
    const float* __restrict__ bp)
{
  __shared__ __align__(16) u16 sh_[32 * 200];
  __shared__ __align__(16) u16 sl_[32 * 200];
  const int tid  = threadIdx.x;
  const int lane = tid & 63;
  const int w    = tid >> 6;
  const int lrow = lane & 15;
  const int lk   = (lane >> 4) * 8;
  const int orow = (lane >> 4) * 4;
  const int tk0  = blockIdx.x * 32;
  const int m0   = w * 48;

  // ---- stage phase-1 A operand: A0 + gm*g2 ----
  #pragma unroll
  for (int it = 0; it < 6; ++it) {
    int idx = tid + it * 256;
    int tokl = idx / 48;
    int c = (idx - tokl * 48) * 4;
    int tok = tk0 + tokl;
    int bb = tok / PP;
    size_t base = (size_t)tok * CC + c;
    float4 v1 = *(const float4*)(A0 + base);
    float4 vg = *(const float4*)(GMg + bb * CC + c);
    float g2 = GS[(size_t)tok * 3 + 2];
    float4 av = make_float4(v1.x + vg.x * g2, v1.y + vg.y * g2,
                            v1.z + vg.z * g2, v1.w + vg.w * g2);
    split4(av, (uint2*)&sh_[tokl * 200 + c], (uint2*)&sl_[tokl * 200 + c]);
  }
  __syncthreads();

#define LOADA_G(WH, WL, KB, AH, AL) { \
    _Pragma("unroll") for (int r = 0; r < 3; ++r) { \
      size_t aoff = (size_t)(m0 + r * 16 + lrow) * 192 + (KB) * 32 + lk; \
      AH[r] = *(const short8v*)(WH + aoff); \
      AL[r] = *(const short8v*)(WL + aoff); } }
#define LOADB_G(KB, BH, BL) { \
    _Pragma("unroll") for (int c = 0; c < 2; ++c) { \
      int tokl = c * 16 + lrow; \
      BH[c] = *(const short8v*)&sh_[tokl * 200 + (KB) * 32 + lk]; \
      BL[c] = *(const short8v*)&sl_[tokl * 200 + (KB) * 32 + lk]; } }
#define GEMM6(WH, WL, ACC) { \
    _Pragma("unroll") for (int kb = 0; kb < 6; ++kb) { \
      short8v ah[3], al[3], bh4[2], bl4[2]; \
      LOADA_G(WH, WL, kb, ah, al); \
      LOADB_G(kb, bh4, bl4); \
      _Pragma("unroll") for (int r = 0; r < 3; ++r) \
        _Pragma("unroll") for (int c = 0; c < 2; ++c) { \
          ACC[r][c] = __builtin_amdgcn_mfma_f32_16x16x32_bf16(ah[r], bh4[c], ACC[r][c], 0, 0, 0); \
          ACC[r][c] = __builtin_amdgcn_mfma_f32_16x16x32_bf16(ah[r], bl4[c], ACC[r][c], 0, 0, 0); \
          ACC[r][c] = __builtin_amdgcn_mfma_f32_16x16x32_bf16(al[r], bh4[c], ACC[r][c], 0, 0, 0); } } }

  // ---- phase 1 GEMM: MOD ----
  f32x4 acc[3][2] = {};
  GEMM6(Wmh, Wml, acc);
  __syncthreads();   // all phase-1 B reads done before MOD overwrites LDS

  // ---- write MOD (+bh) hi/lo into LDS ----
  #pragma unroll
  for (int r = 0; r < 3; ++r) {
    int jb = m0 + r * 16 + orow;
    float4 b4 = *(const float4*)&bh[jb];
    #pragma unroll
    for (int c = 0; c < 2; ++c) {
      int tokl = c * 16 + lrow;
      f32x4 a = acc[r][c];
      float4 mv = make_float4(a[0] + b4.x, a[1] + b4.y, a[2] + b4.z, a[3] + b4.w);
      split4(mv, (uint2*)&sh_[tokl * 200 + jb], (uint2*)&sl_[tokl * 200 + jb]);
    }
  }
  __syncthreads();

  // ---- restage: A2 = q * MOD * mod_t (own-slot read-then-write) ----
  #pragma unroll
  for (int it = 0; it < 6; ++it) {
    int idx = tid + it * 256;
    int tokl = idx / 48;
    int c = (idx - tokl * 48) * 4;
    size_t base = (size_t)(tk0 + tokl) * CC + c;
    float4 q  = *(const float4*)(QS + base);
    float4 mt = *(const float4*)(MTout + base);
    uint2 mh = *(const uint2*)&sh_[tokl * 200 + c];
    uint2 ml = *(const uint2*)&sl_[tokl * 200 + c];
    float m0v = bf2f((u16)(mh.x & 0xffff)) + bf2f((u16)(ml.x & 0xffff));
    float m1v = bf2f((u16)(mh.x >> 16))    + bf2f((u16)(ml.x >> 16));
    float m2v = bf2f((u16)(mh.y & 0xffff)) + bf2f((u16)(ml.y & 0xffff));
    float m3v = bf2f((u16)(mh.y >> 16))    + bf2f((u16)(ml.y >> 16));
    float4 av = make_float4(q.x * m0v * mt.x, q.y * m1v * mt.y,
                            q.z * m2v * mt.z, q.w * m3v * mt.w);
    split4(av, (uint2*)&sh_[tokl * 200 + c], (uint2*)&sl_[tokl * 200 + c]);
  }
  __syncthreads();

  // ---- phase 2 GEMM: out ----
  f32x4 acc2[3][2] = {};
  GEMM6(Wph, Wpl, acc2);
#undef LOADA_G
#undef LOADB_G
#undef GEMM6

  // ---- write out over MT in-place ----
  #pragma unroll
  for (int r = 0; r < 3; ++r) {
    int jb = m0 + r * 16 + orow;
    float4 b4 = *(const float4*)&bp[jb];
    #pragma unroll
    for (int c = 0; c < 2; ++c) {
      int tok = tk0 + c * 16 + lrow;
      f32x4 a = acc2[r][c];
      *(float4*)&MTout[(size_t)tok * CC + jb] =
          make_float4(a[0] + b4.x, a[1] + b4.y, a[2] + b4.z, a[3] + b4.w);
    }
  }
}

extern "C" void kernel_launch(void* const* d_in, const int* in_sizes, int n_in,
                              void* d_out, int out_size, void* d_ws, size_t ws_size,
                              hipStream_t stream)
{
  (void)in_sizes; (void)n_in; (void)out_size; (void)ws_size;
  const float* x   = (const float*)d_in[0];
  const float* Wf  = (const float*)d_in[1];
  const float* bf  = (const float*)d_in[2];
  const float* Wft = (const float*)d_in[3];
  const float* bft = (const float*)d_in[4];
  const float* fw0 = (const float*)d_in[5];
  const float* fw1 = (const float*)d_in[6];
  const float* tw0 = (const float*)d_in[7];
  const float* tw1 = (const float*)d_in[8];
  const float* Wh  = (const float*)d_in[9];
  const float* bh  = (const float*)d_in[10];
  const float* Wht = (const float*)d_in[11];
  const float* bht = (const float*)d_in[12];
  const float* Wp  = (const float*)d_in[13];
  const float* bp  = (const float*)d_in[14];

  float* ws = (float*)d_ws;
  const size_t SZ = (size_t)NTOK * CC;          // 19,267,584 floats (77 MB)
  float* QS     = ws + 0 * SZ;                  // q (spatial)
  float* WS1    = ws + 1 * SZ;                  // ctx_s
  float* WS2    = ws + 2 * SZ;                  // ctx_t -> A0
  float* MT     = (float*)d_out;                // mod_t (spatial order) -> out, in-place
  float* GS     = ws + 3 * SZ;                  // gates_s [tok][3]
  float* GT     = GS + (size_t)NTOK * 3;        // gates_t [n*8+t][3]
  float* GMpart = GT + (size_t)NTOK * 3;        // 49 x 6144
  float* GMg    = GMpart + 49 * 6144;           // gelu(mean) [32][192]
  u16* W3h = (u16*)(GMg + 6144);                // conv3 [k][o][i] hi
  u16* W3l = W3h + 3 * 36864;
  u16* W5h = W3l + 3 * 36864;
  u16* W5l = W5h + 5 * 36864;
  u16* WHh = W5l + 5 * 36864;
  u16* WHl = WHh + 36864;
  u16* WIh = WHl + 36864;                       // input proj [j<768][k]
  u16* WIl = WIh + 768 * 192;
  u16* Wmh = WIl + 768 * 192;                   // Wh [o][c]
  u16* Wml = Wmh + 36864;
  u16* Wph = Wml + 36864;                       // Wp^T [o][c]
  u16* Wpl = Wph + 36864;

  k_wsplit<<<432, 256, 0, stream>>>(tw0, W3h, W3l, 3);
  k_wsplit<<<720, 256, 0, stream>>>(tw1, W5h, W5l, 5);
  k_wsplit<<<144, 256, 0, stream>>>(Wht, WHh, WHl, 1);
  k_wsplit_in<<<576, 256, 0, stream>>>(Wf, Wft, WIh, WIl);
  k_wsplit_d<<<144, 256, 0, stream>>>(Wh, Wmh, Wml);
  k_wsplit_t<<<144, 256, 0, stream>>>(Wp, Wph, Wpl);

  k_in_mfma<<<dim3(3136, 2), 256, 0, stream>>>(x, WIh, WIl, bf, bft,
                                               QS, WS1, GS, WS2, GT);
  k_t_mfma<<<3136, 256, 0, stream>>>(WS2, GT, W3h, W5h, WHh, WHl, bht, MT);

  k_dwf<<<dim3(49, 6, 32), 256, 0, stream>>>(WS1, GS, fw0, fw1, WS2, GMpart);
  k_gmg<<<24, 256, 0, stream>>>(GMpart, GMg);

  k_modout<<<3136, 256, 0, stream>>>(WS2, GS, GMg, Wmh, Wml, bh,
                                     QS, MT, Wph, Wpl, bp);
}